// Round 1
// baseline (51593.628 us; speedup 1.0000x reference)
//
#include <hip/hip_runtime.h>
#include <hip/hip_bf16.h>
#include <stdint.h>

typedef __attribute__((ext_vector_type(8))) short short8;
typedef __attribute__((ext_vector_type(4))) float f32x4;

// ---------- bf16 helpers (bit-exact RNE, no API dependence) ----------
static __device__ __forceinline__ unsigned short f2bf(float f) {
    uint32_t u = __float_as_uint(f);
    u = u + 0x7fffu + ((u >> 16) & 1u);   // round-to-nearest-even
    return (unsigned short)(u >> 16);
}
static __device__ __forceinline__ float bf2f(unsigned short u) {
    return __uint_as_float(((uint32_t)u) << 16);
}

// ---------- sizes ----------
#define NB   128
#define NS   512
#define NH   1024
// ws element offsets (ushort units)
#define O_WZR_HI 0L
#define O_WZR_LO 4194304L            // 2048*2048
#define O_WNX_HI 8388608L
#define O_WNX_LO 9437184L            // +1024*1024
#define O_WNH_HI 10485760L
#define O_WNH_LO 11534336L
#define O_XBF    12582912L           // [512][128][1024] bf16
#define O_HBF    (12582912L + 67108864L)
#define O_HF32   (O_HBF + 262144L)   // 2 ping-pong bf16 h bufs, then f32 h

// ---------- prep: split weights into bf16 hi/lo, laid out as B^T rows ----------
__global__ void prep_w(const float* __restrict__ Wih, const float* __restrict__ Whh,
                       unsigned short* __restrict__ wzr_hi, unsigned short* __restrict__ wzr_lo,
                       unsigned short* __restrict__ wnx_hi, unsigned short* __restrict__ wnx_lo,
                       unsigned short* __restrict__ wnh_hi, unsigned short* __restrict__ wnh_lo)
{
    long i = (long)blockIdx.x * 256 + threadIdx.x;      // 6291456 total
    if (i >= 6291456L) return;
    float w; unsigned short *ph, *pl; long o;
    if (i < 4194304L) {                // z,r rows: [g in 0..2048) x [k in 0..2048) cat(Wih,Whh)
        long g = i >> 11, k = i & 2047;
        w = (k < 1024) ? Wih[g * 1024 + k] : Whh[g * 1024 + (k - 1024)];
        ph = wzr_hi; pl = wzr_lo; o = i;
    } else if (i < 5242880L) {         // n-gate, x part: W_ih rows 2048..3071
        o = i - 4194304L; long jj = o >> 10, k = o & 1023;
        w = Wih[(2048 + jj) * 1024 + k]; ph = wnx_hi; pl = wnx_lo;
    } else {                           // n-gate, h part: W_hh rows 2048..3071
        o = i - 5242880L; long jj = o >> 10, k = o & 1023;
        w = Whh[(2048 + jj) * 1024 + k]; ph = wnh_hi; pl = wnh_lo;
    }
    unsigned short hi = f2bf(w);
    ph[o] = hi;
    pl[o] = f2bf(w - bf2f(hi));
}

// ---------- prep: x (B,S,I) f32 -> (S,B,I) bf16 ----------
__global__ void prep_x(const float* __restrict__ x, unsigned short* __restrict__ xbf)
{
    long t = (long)blockIdx.x * 256 + threadIdx.x;      // 8388608 threads, 8 elems each
    long base = t * 8;
    if (base >= 67108864L) return;
    long b = base >> 19;                // / (512*1024)
    long rem = base & 524287L;
    long s = rem >> 10;
    long k = rem & 1023L;
    const float4* xp = (const float4*)(x + base);
    float4 v0 = xp[0], v1 = xp[1];
    short8 sv;
    sv[0] = (short)f2bf(v0.x); sv[1] = (short)f2bf(v0.y);
    sv[2] = (short)f2bf(v0.z); sv[3] = (short)f2bf(v0.w);
    sv[4] = (short)f2bf(v1.x); sv[5] = (short)f2bf(v1.y);
    sv[6] = (short)f2bf(v1.z); sv[7] = (short)f2bf(v1.w);
    *(short8*)(xbf + ((s * 128 + b) << 10) + k) = sv;
}

// ---------- prep: h0 -> h_f32, h_bf16[0], and hn output tail ----------
__global__ void prep_h(const float* __restrict__ h0, float* __restrict__ hf,
                       unsigned short* __restrict__ hbf, float* __restrict__ outTail)
{
    int i = blockIdx.x * 256 + threadIdx.x;             // 131072
    float v = h0[i];
    hf[i] = v;
    hbf[i] = f2bf(v);
    outTail[i] = v;
}

// ---------- one recurrence step ----------
// grid 64 blocks (16 output cols each), 512 threads = 8 waves (16 batches each)
__global__ __launch_bounds__(512) void gru_step(
    const unsigned short* __restrict__ xbf,
    const unsigned short* __restrict__ wzr_hi, const unsigned short* __restrict__ wzr_lo,
    const unsigned short* __restrict__ wnx_hi, const unsigned short* __restrict__ wnx_lo,
    const unsigned short* __restrict__ wnh_hi, const unsigned short* __restrict__ wnh_lo,
    unsigned short* __restrict__ hbf, float* __restrict__ hf,
    const float* __restrict__ bias, float* __restrict__ out, int s)
{
    const int tid  = threadIdx.x;
    const int wave = tid >> 6, lane = tid & 63;
    const int j0   = blockIdx.x << 4;
    const int row  = lane & 15;          // A row within m-tile / B col within n-tile
    const int kg   = lane >> 4;          // k sub-group (8 contiguous k each)

    const unsigned short* xs = xbf + ((long)s << 17) + ((wave << 4) + row) * 1024 + (kg << 3);
    const unsigned short* hs = hbf + ((long)(s & 1) << 17) + ((wave << 4) + row) * 1024 + (kg << 3);
    const long wzoff = (long)(j0 + row) * 2048 + (kg << 3);
    const long wroff = (long)(1024 + j0 + row) * 2048 + (kg << 3);
    const long wnoff = (long)(j0 + row) * 1024 + (kg << 3);
    const unsigned short* bzh = wzr_hi + wzoff;
    const unsigned short* bzl = wzr_lo + wzoff;
    const unsigned short* brh = wzr_hi + wroff;
    const unsigned short* brl = wzr_lo + wroff;
    const unsigned short* bxh = wnx_hi + wnoff;
    const unsigned short* bxl = wnx_lo + wnoff;
    const unsigned short* bhh = wnh_hi + wnoff;
    const unsigned short* bhl = wnh_lo + wnoff;

    f32x4 az = {0,0,0,0}, ar = {0,0,0,0}, anx = {0,0,0,0}, anh = {0,0,0,0};
    #define LD8(p) (*(const short8*)(p))
    #define MFMA(a, b, c) __builtin_amdgcn_mfma_f32_16x16x32_bf16((a), (b), (c), 0, 0, 0)

    #pragma unroll 4
    for (int kt = 0; kt < 32; ++kt) {   // x part of K
        short8 a = LD8(xs + kt * 32);
        az  = MFMA(a, LD8(bzh + kt * 32), az);
        az  = MFMA(a, LD8(bzl + kt * 32), az);
        ar  = MFMA(a, LD8(brh + kt * 32), ar);
        ar  = MFMA(a, LD8(brl + kt * 32), ar);
        anx = MFMA(a, LD8(bxh + kt * 32), anx);
        anx = MFMA(a, LD8(bxl + kt * 32), anx);
    }
    #pragma unroll 4
    for (int kt = 0; kt < 32; ++kt) {   // h part of K
        short8 a = LD8(hs + kt * 32);
        az  = MFMA(a, LD8(bzh + 1024 + kt * 32), az);
        az  = MFMA(a, LD8(bzl + 1024 + kt * 32), az);
        ar  = MFMA(a, LD8(brh + 1024 + kt * 32), ar);
        ar  = MFMA(a, LD8(brl + 1024 + kt * 32), ar);
        anh = MFMA(a, LD8(bhh + kt * 32), anh);
        anh = MFMA(a, LD8(bhl + kt * 32), anh);
    }

    // epilogue: C/D mapping col=lane&15, row=(lane>>4)*4+i
    const int j = j0 + row;
    const float bz = bias[j], br = bias[1024 + j], bn = bias[2048 + j];
    unsigned short* hw = hbf + ((long)((s + 1) & 1) << 17);
    #pragma unroll
    for (int i = 0; i < 4; ++i) {
        int b = (wave << 4) + (kg << 2) + i;
        float z = 1.0f / (1.0f + __expf(-(az[i] + bz)));
        float r = 1.0f / (1.0f + __expf(-(ar[i] + br)));
        float ghn = anh[i];
        float inner = anx[i] + bn + ghn + r * (ghn + bn);
        float e2 = __expf(2.0f * inner);
        float n = 1.0f - 2.0f / (e2 + 1.0f);            // tanh(inner)
        long o = ((long)b << 10) + j;
        float hp = hf[o];
        float hv = (1.0f - z) * n + z * hp;
        hf[o] = hv;
        hw[o] = f2bf(hv);
        out[((long)b << 19) + ((long)s << 10) + j] = hv;
    }
}

extern "C" void kernel_launch(void* const* d_in, const int* in_sizes, int n_in,
                              void* d_out, int out_size, void* d_ws, size_t ws_size,
                              hipStream_t stream)
{
    const float* x    = (const float*)d_in[0];
    const float* Wih  = (const float*)d_in[1];
    const float* Whh  = (const float*)d_in[2];
    const float* bias = (const float*)d_in[3];
    const float* h0   = (const float*)d_in[4];
    float* out = (float*)d_out;

    unsigned short* ws16 = (unsigned short*)d_ws;
    unsigned short* wzr_hi = ws16 + O_WZR_HI;
    unsigned short* wzr_lo = ws16 + O_WZR_LO;
    unsigned short* wnx_hi = ws16 + O_WNX_HI;
    unsigned short* wnx_lo = ws16 + O_WNX_LO;
    unsigned short* wnh_hi = ws16 + O_WNH_HI;
    unsigned short* wnh_lo = ws16 + O_WNH_LO;
    unsigned short* xbf    = ws16 + O_XBF;
    unsigned short* hbf    = ws16 + O_HBF;
    float*          hf     = (float*)(ws16 + O_HF32);

    prep_w<<<24576, 256, 0, stream>>>(Wih, Whh, wzr_hi, wzr_lo, wnx_hi, wnx_lo, wnh_hi, wnh_lo);
    prep_x<<<32768, 256, 0, stream>>>(x, xbf);
    prep_h<<<512, 256, 0, stream>>>(h0, hf, hbf, out + 67108864L);

    for (int s = 0; s < NS; ++s) {
        gru_step<<<64, 512, 0, stream>>>(xbf, wzr_hi, wzr_lo, wnx_hi, wnx_lo,
                                         wnh_hi, wnh_lo, hbf, hf, bias, out, s);
    }
}

// Round 2
// 11744.962 us; speedup vs baseline: 4.3928x; 4.3928x over previous
//
#include <hip/hip_runtime.h>
#include <stdint.h>

typedef __attribute__((ext_vector_type(8))) short short8;
typedef __attribute__((ext_vector_type(4))) float f32x4;

// ---------- bf16 helpers (bit-exact RNE) ----------
static __device__ __forceinline__ unsigned short f2bf(float f) {
    uint32_t u = __float_as_uint(f);
    u = u + 0x7fffu + ((u >> 16) & 1u);   // round-to-nearest-even
    return (unsigned short)(u >> 16);
}
static __device__ __forceinline__ float bf2f(unsigned short u) {
    return __uint_as_float(((uint32_t)u) << 16);
}

// ---------- ws element offsets (ushort units) ----------
#define O_PW   0L            // [256 blk][2 hi/lo][12 row][2048 k] = 12,582,912
#define O_XBF  12582912L     // [512][128][1024] bf16
#define O_HBF  79691776L     // 2 ping-pong bf16 h bufs (2*131072)
#define O_HF32 79953920L     // 131072 f32 master h

// ---------- prep: pack split weights per block: [blk][hl][row<12][k<2048] ----------
// row: 0-3 = z cols j0..j0+3, 4-7 = r, 8-11 = n; k<1024 -> W_ih, else W_hh
__global__ void prep_w(const float* __restrict__ Wih, const float* __restrict__ Whh,
                       unsigned short* __restrict__ pw)
{
    long i = (long)blockIdx.x * 256 + threadIdx.x;   // 6,291,456 total
    if (i >= 6291456L) return;
    int k = (int)(i & 2047);
    long t = i >> 11;
    int row = (int)(t % 12);
    int blk = (int)(t / 12);
    int g = row >> 2;
    int jj = (blk << 2) + (row & 3);
    float w = (k < 1024) ? Wih[((long)((g << 10) + jj) << 10) + k]
                         : Whh[((long)((g << 10) + jj) << 10) + (k - 1024)];
    unsigned short hi = f2bf(w);
    unsigned short lo = f2bf(w - bf2f(hi));
    long base = (long)blk * 49152;
    pw[base + (long)row * 2048 + k] = hi;
    pw[base + 24576L + (long)row * 2048 + k] = lo;
}

// ---------- prep: x (B,S,I) f32 -> (S,B,I) bf16 ----------
__global__ void prep_x(const float* __restrict__ x, unsigned short* __restrict__ xbf)
{
    long t = (long)blockIdx.x * 256 + threadIdx.x;
    long base = t * 8;
    if (base >= 67108864L) return;
    long b = base >> 19;
    long rem = base & 524287L;
    long s = rem >> 10;
    long k = rem & 1023L;
    const float4* xp = (const float4*)(x + base);
    float4 v0 = xp[0], v1 = xp[1];
    short8 sv;
    sv[0] = (short)f2bf(v0.x); sv[1] = (short)f2bf(v0.y);
    sv[2] = (short)f2bf(v0.z); sv[3] = (short)f2bf(v0.w);
    sv[4] = (short)f2bf(v1.x); sv[5] = (short)f2bf(v1.y);
    sv[6] = (short)f2bf(v1.z); sv[7] = (short)f2bf(v1.w);
    *(short8*)(xbf + ((s * 128 + b) << 10) + k) = sv;
}

// ---------- prep: h0 -> h_f32, h_bf16[0], and hn output tail ----------
__global__ void prep_h(const float* __restrict__ h0, float* __restrict__ hf,
                       unsigned short* __restrict__ hbf, float* __restrict__ outTail)
{
    int i = blockIdx.x * 256 + threadIdx.x;          // 131072
    float v = h0[i];
    hf[i] = v;
    hbf[i] = f2bf(v);
    outTail[i] = v;
}

// ---------- one recurrence step ----------
// 256 blocks (1/CU) x 4 h-cols; 512 thr = 8 waves.
// waves 0-3: x-half of K (m-tiles 2w,2w+1); waves 4-7: h-half (same m-tiles).
// Weights staged in LDS (hi/lo, 12 rows, stride 2056 = conflict-free b128).
__global__ __launch_bounds__(512) void gru_step(
    const unsigned short* __restrict__ xbf,
    const unsigned short* __restrict__ pw,
    unsigned short* __restrict__ hbf, float* __restrict__ hf,
    const float* __restrict__ bias, float* __restrict__ out, int s)
{
    __shared__ unsigned short lds_w[2 * 12 * 2056];  // 98,688 B

    const int tid  = threadIdx.x;
    const int wave = tid >> 6, lane = tid & 63;
    const int j0   = blockIdx.x << 2;

    // ---- stage weights: pw[blk] (49,152 ushorts) -> LDS (padded rows) ----
    {
        const unsigned short* src = pw + (long)blockIdx.x * 49152;
        #pragma unroll
        for (int it = 0; it < 12; ++it) {
            int idx = it * 512 + tid;               // 6144 chunks of 8
            int e = idx << 3;
            int hl = (e >= 24576) ? 1 : 0;
            int rem = e - hl * 24576;
            int row = rem >> 11;
            int k = rem & 2047;
            *(short8*)&lds_w[(hl * 12 + row) * 2056 + k] = *(const short8*)(src + e);
        }
    }
    __syncthreads();

    const int half = wave >> 2;          // 0 = x part, 1 = h part
    const int w4   = wave & 3;           // m-tile pair index
    const int row  = lane & 15, kg = lane >> 4;
    const int rl   = (row < 12) ? row : (row - 8);   // lanes 12-15: same-addr broadcast

    const unsigned short* abase = half ? (hbf + ((long)(s & 1) << 17))
                                       : (xbf + ((long)s << 17));
    const unsigned short* a0 = abase + (((w4 << 1) + 0) * 16 + row) * 1024 + (kg << 3);
    const unsigned short* a1 = abase + (((w4 << 1) + 1) * 16 + row) * 1024 + (kg << 3);
    const unsigned short* bh = lds_w + rl * 2056 + (half << 10) + (kg << 3);
    const unsigned short* bl = bh + 12 * 2056;

    f32x4 acc0 = {0,0,0,0}, acc1 = {0,0,0,0};
    #define LD8(p)     (*(const short8*)(p))
    #define MFMA(a,b,c) __builtin_amdgcn_mfma_f32_16x16x32_bf16((a),(b),(c),0,0,0)

    #pragma unroll 4
    for (int kt = 0; kt < 32; ++kt) {
        short8 fa0 = LD8(a0 + kt * 32);
        short8 fa1 = LD8(a1 + kt * 32);
        short8 fbh = LD8(bh + kt * 32);
        short8 fbl = LD8(bl + kt * 32);
        acc0 = MFMA(fa0, fbh, acc0);
        acc0 = MFMA(fa0, fbl, acc0);
        acc1 = MFMA(fa1, fbh, acc1);
        acc1 = MFMA(fa1, fbl, acc1);
    }

    // ---- combine x-part and h-part partials via LDS exchange ----
    __syncthreads();                      // all weight ds_reads done; safe to alias
    f32x4* xch = (f32x4*)lds_w;           // [8 m-tiles][64 lanes]
    if (half) {
        xch[((w4 << 1) + 0) * 64 + lane] = acc0;
        xch[((w4 << 1) + 1) * 64 + lane] = acc1;
    }
    __syncthreads();

    if (!half) {
        const int c = row;                // col within n-tile: 0-3=z, 4-7=r, 8-11=n
        const float bz = bias[j0 + (c & 3)];
        const float br = bias[1024 + j0 + (c & 3)];
        const float bn = bias[2048 + j0 + (c & 3)];
        unsigned short* hw = hbf + ((long)((s + 1) & 1) << 17);
        #pragma unroll
        for (int mi = 0; mi < 2; ++mi) {
            f32x4 sx = mi ? acc1 : acc0;
            f32x4 sh = xch[((w4 << 1) + mi) * 64 + lane];
            #pragma unroll
            for (int i = 0; i < 4; ++i) {
                float sxv = sx[i], shv = sh[i];
                float vx4 = __shfl(sxv, lane + 4);   // r-gate partials (col c+4)
                float vh4 = __shfl(shv, lane + 4);
                float vx8 = __shfl(sxv, lane + 8);   // n-gate partials (col c+8)
                float vh8 = __shfl(shv, lane + 8);
                if (c < 4) {
                    int b = ((w4 << 1) + mi) * 16 + (kg << 2) + i;
                    int j = j0 + c;
                    float z = 1.f / (1.f + __expf(-(sxv + shv + bz)));
                    float r = 1.f / (1.f + __expf(-(vx4 + vh4 + br)));
                    float inner = vx8 + bn + vh8 + r * (vh8 + bn);
                    float e2 = __expf(2.f * inner);
                    float n = 1.f - 2.f / (e2 + 1.f);         // tanh(inner)
                    long o = ((long)b << 10) + j;
                    float hp = hf[o];
                    float hv = (1.f - z) * n + z * hp;
                    hf[o] = hv;
                    hw[o] = f2bf(hv);
                    out[((long)b << 19) + ((long)s << 10) + j] = hv;
                }
            }
        }
    }
}

extern "C" void kernel_launch(void* const* d_in, const int* in_sizes, int n_in,
                              void* d_out, int out_size, void* d_ws, size_t ws_size,
                              hipStream_t stream)
{
    const float* x    = (const float*)d_in[0];
    const float* Wih  = (const float*)d_in[1];
    const float* Whh  = (const float*)d_in[2];
    const float* bias = (const float*)d_in[3];
    const float* h0   = (const float*)d_in[4];
    float* out = (float*)d_out;

    unsigned short* ws16 = (unsigned short*)d_ws;
    unsigned short* pw   = ws16 + O_PW;
    unsigned short* xbf  = ws16 + O_XBF;
    unsigned short* hbf  = ws16 + O_HBF;
    float*          hf   = (float*)(ws16 + O_HF32);

    prep_w<<<24576, 256, 0, stream>>>(Wih, Whh, pw);
    prep_x<<<32768, 256, 0, stream>>>(x, xbf);
    prep_h<<<512, 256, 0, stream>>>(h0, hf, hbf, out + 67108864L);

    for (int s = 0; s < 512; ++s) {
        gru_step<<<256, 512, 0, stream>>>(xbf, pw, hbf, hf, bias, out, s);
    }
}